// Round 10
// baseline (579.506 us; speedup 1.0000x reference)
//
#include <hip/hip_runtime.h>
#include <hip/hip_bf16.h>
#include <float.h>

#define NEG 0.2f
#define SEGSHIFT 13   // src-range segments of 8192 nodes

__device__ __forceinline__ float leaky(float x) { return x > 0.0f ? x : NEG * x; }

__device__ __forceinline__ unsigned short f2bf(float f) {
  unsigned x = __float_as_uint(f);
  unsigned r = (x + 0x7fffu + ((x >> 16) & 1u)) >> 16;  // round-to-nearest-even
  return (unsigned short)r;
}

__device__ __forceinline__ float2 bf2f2(unsigned u) {   // u = (ch1<<16)|ch0
  float2 r;
  r.x = __uint_as_float(u << 16);
  r.y = __uint_as_float(u & 0xffff0000u);
  return r;
}

using frag8 = __attribute__((ext_vector_type(8))) short;   // 8 bf16
using f32x4v = __attribute__((ext_vector_type(4))) float;  // 4 fp32 acc

// ---------------------------------------------------------------- utilities
__global__ void zero_kernel(int* __restrict__ p, int n) {
  int i = blockIdx.x * blockDim.x + threadIdx.x;
  int stride = gridDim.x * blockDim.x;
  for (; i < n; i += stride) p[i] = 0;
}

__global__ void xcvt_kernel(const float* __restrict__ x, unsigned short* __restrict__ xb, int n) {
  int i = blockIdx.x * blockDim.x + threadIdx.x;
  if (i < n) xb[i] = f2bf(x[i]);
}

// count per (dst, src-segment) bucket
__global__ void count_kernel(const int* __restrict__ ei, int* __restrict__ degseg,
                             int E, int N, int nseg) {
  int i = blockIdx.x * blockDim.x + threadIdx.x;
  if (i >= E + N) return;
  int src, dst;
  if (i < E) { src = ei[i]; dst = ei[E + i]; } else { src = dst = i - E; }
  atomicAdd(&degseg[(size_t)dst * nseg + (src >> SEGSHIFT)], 1);
}

__global__ __launch_bounds__(1024) void scan_block_kernel(const int* __restrict__ deg,
                                                          int* __restrict__ row_start,
                                                          int* __restrict__ sums, int n) {
  __shared__ int buf[1024];
  int t = threadIdx.x;
  int idx = blockIdx.x * 1024 + t;
  int x = (idx < n) ? deg[idx] : 0;
  int v = x;
  buf[t] = v;
  __syncthreads();
  for (int off = 1; off < 1024; off <<= 1) {
    int a = (t >= off) ? buf[t - off] : 0;
    __syncthreads();
    v += a;
    buf[t] = v;
    __syncthreads();
  }
  if (idx < n) row_start[idx] = v - x;  // local exclusive
  if (t == 1023) sums[blockIdx.x] = v;  // chunk total
}

__global__ __launch_bounds__(1024) void scan_sums_kernel(int* __restrict__ sums,
                                                         int* __restrict__ row_start,
                                                         int nch, int n) {
  __shared__ int buf[1024];
  int t = threadIdx.x;
  int x = (t < nch) ? sums[t] : 0;
  int v = x;
  buf[t] = v;
  __syncthreads();
  for (int off = 1; off < 1024; off <<= 1) {
    int a = (t >= off) ? buf[t - off] : 0;
    __syncthreads();
    v += a;
    buf[t] = v;
    __syncthreads();
  }
  if (t < nch) sums[t] = v - x;        // exclusive chunk offsets
  if (t == 1023) row_start[n] = v;     // grand total
}

__global__ __launch_bounds__(1024) void scan_add_kernel(int* __restrict__ row_start,
                                                        const int* __restrict__ sums, int n) {
  int idx = blockIdx.x * 1024 + threadIdx.x;
  if (idx < n) row_start[idx] += sums[blockIdx.x];
}

// single-pass fill into (dst, src-segment) buckets
__global__ void fill_kernel(const int* __restrict__ ei, int* __restrict__ cursor,
                            const int* __restrict__ rowseg, int* __restrict__ csr_src,
                            int* __restrict__ csr_dst, int E, int N, int nseg) {
  int i = blockIdx.x * blockDim.x + threadIdx.x;
  if (i >= E + N) return;
  int src, dst;
  if (i < E) { src = ei[i]; dst = ei[E + i]; } else { src = dst = i - E; }
  size_t b = (size_t)dst * nseg + (src >> SEGSHIFT);
  int pos = atomicAdd(&cursor[b], 1);
  int slot = rowseg[b] + pos;
  csr_src[slot] = src;
  csr_dst[slot] = dst;
}

// ---------------------------------------------------------------- MFMA GEMM  Hh = bf16(Xb @ W) head-plane, fused alpha dots
// Hh layout: [head][N][32] bf16 (3.2 MB planes -> L2-resident per-head gathers)
__global__ __launch_bounds__(256) void gemm_kernel(const unsigned short* __restrict__ Xb,
                                                   const float* __restrict__ W,
                                                   unsigned short* __restrict__ Hh,
                                                   const float* __restrict__ a_src,
                                                   const float* __restrict__ a_dst,
                                                   float* __restrict__ as_arr,
                                                   float* __restrict__ ad_arr,
                                                   int nrows, int K) {
  __shared__ unsigned short Wt[128][136];  // [n][k] bf16 (transposed W)
  __shared__ unsigned short Xs[64][136];   // [row][k] bf16; reused for C transpose
  int t = threadIdx.x;
  int wave = t >> 6, lane = t & 63;
  int n0 = lane & 15, quad = lane >> 4;
  int row0 = blockIdx.x * 64, wrow = wave * 16;

  for (int idx = t; idx < K * 128; idx += 256) {
    int k = idx >> 7, n = idx & 127;
    Wt[n][k] = f2bf(W[idx]);
  }
  int rowElems = K >> 3;
  for (int idx = t; idx < 64 * rowElems; idx += 256) {
    int r = idx / rowElems, c8 = idx % rowElems;
    int gr = row0 + r;
    uint4 v = make_uint4(0, 0, 0, 0);
    if (gr < nrows) v = *(const uint4*)(Xb + (size_t)gr * K + c8 * 8);
    *(uint4*)(&Xs[r][c8 * 8]) = v;
  }
  __syncthreads();

  f32x4v acc[8];
#pragma unroll
  for (int c = 0; c < 8; ++c) acc[c] = (f32x4v){0.f, 0.f, 0.f, 0.f};

  for (int kb = 0; kb < K; kb += 32) {
    frag8 a = *(const frag8*)(&Xs[wrow + n0][kb + quad * 8]);
#pragma unroll
    for (int c = 0; c < 8; ++c) {
      frag8 b = *(const frag8*)(&Wt[c * 16 + n0][kb + quad * 8]);
      acc[c] = __builtin_amdgcn_mfma_f32_16x16x32_bf16(a, b, acc[c], 0, 0, 0);
    }
  }

  float asv[8], adv[8];
#pragma unroll
  for (int c = 0; c < 8; ++c) {
    asv[c] = a_src[c * 16 + n0];
    adv[c] = a_dst[c * 16 + n0];
  }
#pragma unroll
  for (int r = 0; r < 4; ++r) {
    float ps[4] = {0.f, 0.f, 0.f, 0.f}, pd[4] = {0.f, 0.f, 0.f, 0.f};
#pragma unroll
    for (int c = 0; c < 8; ++c) {
      int h = c >> 1;
      ps[h] += acc[c][r] * asv[c];
      pd[h] += acc[c][r] * adv[c];
    }
#pragma unroll
    for (int off = 1; off < 16; off <<= 1) {
#pragma unroll
      for (int h = 0; h < 4; ++h) {
        ps[h] += __shfl_xor(ps[h], off);
        pd[h] += __shfl_xor(pd[h], off);
      }
    }
    if (n0 == 0) {
      int m = row0 + wrow + quad * 4 + r;
      if (m < nrows) {
#pragma unroll
        for (int h = 0; h < 4; ++h) {
          as_arr[(size_t)m * 4 + h] = ps[h];
          ad_arr[(size_t)m * 4 + h] = pd[h];
        }
      }
    }
  }

  __syncthreads();
#pragma unroll
  for (int c = 0; c < 8; ++c)
#pragma unroll
    for (int r = 0; r < 4; ++r)
      Xs[wrow + quad * 4 + r][c * 16 + n0] = f2bf(acc[c][r]);
  __syncthreads();
  // head-plane store: chunk c8 covers channels c8*8..c8*8+7 -> head c8>>2, offset (c8&3)*8
  for (int idx = t; idx < 64 * 16; idx += 256) {
    int r = idx >> 4, c8 = idx & 15;
    int gr = row0 + r;
    if (gr < nrows)
      *(uint4*)(Hh + ((size_t)(c8 >> 2) * nrows + gr) * 32 + (c8 & 3) * 8) =
          *(const uint4*)(&Xs[r][c8 * 8]);
  }
}

// ---------------------------------------------------------------- per-edge exp(leaky(logit)), head-plane layout
__global__ __launch_bounds__(256) void ecomp_kernel(const int* __restrict__ csr_src,
                                                    const int* __restrict__ csr_dst,
                                                    const float* __restrict__ as_arr,
                                                    const float* __restrict__ ad_arr,
                                                    float* __restrict__ eh, int Etot) {
  int i = blockIdx.x * 256 + threadIdx.x;
  if (i >= Etot) return;
  int s = csr_src[i];
  int d = csr_dst[i];
  float4 a = *(const float4*)(as_arr + (size_t)s * 4);
  float4 b = *(const float4*)(ad_arr + (size_t)d * 4);
  eh[i]                    = __expf(fminf(leaky(a.x + b.x), 80.f));
  eh[(size_t)Etot + i]     = __expf(fminf(leaky(a.y + b.y), 80.f));
  eh[(size_t)2 * Etot + i] = __expf(fminf(leaky(a.z + b.z), 80.f));
  eh[(size_t)3 * Etot + i] = __expf(fminf(leaky(a.w + b.w), 80.f));
}

// ---------------------------------------------------------------- aggregation v9: phase-locked per-head, L2-resident planes
// grid = 4 heads x nb nodeblocks, head-major (all head-0 blocks dispatch first).
// wave = one node: 4 edge-slots (q) x 16 channel-lanes (ql owns packed pair 2ql,2ql+1).
// gather = 64B contiguous row from the head's 3.2MB plane.
template <int POOL>
__global__ __launch_bounds__(256) void agg_kernel(const unsigned short* __restrict__ Hh,
                                                  const float* __restrict__ eh,
                                                  const int* __restrict__ csr_src,
                                                  const int* __restrict__ rowseg,
                                                  const float* __restrict__ bias,
                                                  unsigned short* __restrict__ xnext,
                                                  const int* __restrict__ batch,
                                                  float* __restrict__ pooled,
                                                  int N, int nseg, int Etot, int nb) {
  int wid = threadIdx.x >> 6;
  int lane = threadIdx.x & 63;
  int q = lane >> 4, ql = lane & 15;
  int h = blockIdx.x / nb;
  int n = (blockIdx.x % nb) * 4 + wid;
  if (n >= N) return;
  int rs = rowseg[(size_t)n * nseg];
  int re = rowseg[(size_t)n * nseg + nseg];

  const unsigned* hb = (const unsigned*)Hh + (size_t)h * N * 16;  // plane rows = 16 dwords
  const float* ep = eh + (size_t)h * Etot;
  float acc0 = 0.f, acc1 = 0.f, den = 0.f;

  for (int i = rs; i < re; i += 8) {
    int i0 = i + q, i1 = i + 4 + q;
    int j0 = i0 < re ? i0 : rs;            // safe slot (deg>=1 from self-loop)
    int j1 = i1 < re ? i1 : rs;
    int s0 = csr_src[j0], s1 = csr_src[j1];
    float e0 = i0 < re ? ep[j0] : 0.f;
    float e1 = i1 < re ? ep[j1] : 0.f;
    unsigned u0 = hb[(size_t)s0 * 16 + ql];
    unsigned u1 = hb[(size_t)s1 * 16 + ql];
    float2 f0 = bf2f2(u0), f1 = bf2f2(u1);
    den += e0 + e1;
    acc0 += e0 * f0.x + e1 * f1.x;
    acc1 += e0 * f0.y + e1 * f1.y;
  }
  // cross-quarter reduce (quarters hold disjoint edge subsets)
  acc0 += __shfl_xor(acc0, 16); acc0 += __shfl_xor(acc0, 32);
  acc1 += __shfl_xor(acc1, 16); acc1 += __shfl_xor(acc1, 32);
  den  += __shfl_xor(den, 16);  den  += __shfl_xor(den, 32);

  if (q == 0) {
    float inv = 1.0f / (den + 1e-16f);
    int ch = h * 32 + 2 * ql;
    float2 bv = *(const float2*)(bias + ch);
    float v0 = leaky(acc0 * inv + bv.x);
    float v1 = leaky(acc1 * inv + bv.y);
    if (POOL) {
      int g = batch[n];
      atomicAdd(&pooled[(size_t)g * 128 + ch], v0);
      atomicAdd(&pooled[(size_t)g * 128 + ch + 1], v1);
    } else {
      unsigned pk = ((unsigned)f2bf(v1) << 16) | (unsigned)f2bf(v0);
      ((unsigned*)xnext)[(size_t)n * 64 + h * 16 + ql] = pk;
    }
  }
}

// ---------------------------------------------------------------- head
__global__ void head_kernel(const float* __restrict__ pooled, const float* __restrict__ fc_w,
                            const float* __restrict__ fc_b, const float* __restrict__ bn_g,
                            const float* __restrict__ bn_b, float* __restrict__ out, int G) {
  int t = threadIdx.x;
  int g = blockIdx.x * 8 + (t >> 5);
  int j = t & 31;
  if (g >= G) return;
  const float* pr = pooled + (size_t)g * 128;
  float acc = 0.f;
#pragma unroll 8
  for (int k = 0; k < 128; ++k) acc += pr[k] * fc_w[k * 32 + j];
  const float inv = 0.9999950000374997f;  // 1/sqrt(1+1e-5)
  out[g * 32 + j] = bn_g[j] * (acc + fc_b[j]) * inv + bn_b[j];
}

// ---------------------------------------------------------------- launch
extern "C" void kernel_launch(void* const* d_in, const int* in_sizes, int n_in,
                              void* d_out, int out_size, void* d_ws, size_t ws_size,
                              hipStream_t stream) {
  const float* x = (const float*)d_in[0];
  const int* ei = (const int*)d_in[1];
  const int* batch = (const int*)d_in[2];
  const float* Wm[3] = {(const float*)d_in[3], (const float*)d_in[7], (const float*)d_in[11]};
  const float* a_s[3] = {(const float*)d_in[4], (const float*)d_in[8], (const float*)d_in[12]};
  const float* a_d[3] = {(const float*)d_in[5], (const float*)d_in[9], (const float*)d_in[13]};
  const float* bb[3] = {(const float*)d_in[6], (const float*)d_in[10], (const float*)d_in[14]};
  const float* fc_w = (const float*)d_in[15];
  const float* fc_b = (const float*)d_in[16];
  const float* bn_g = (const float*)d_in[17];
  const float* bn_b = (const float*)d_in[18];
  float* out = (float*)d_out;

  int N = in_sizes[0] / 64;
  int E = in_sizes[1] / 2;
  int G = out_size / 32;
  int Etot = E + N;
  int nseg = ((N - 1) >> SEGSHIFT) + 1;
  int L = N * nseg;   // bucket count

  char* p = (char*)d_ws;
  auto carve = [&](size_t bytes) {
    char* r = p;
    p += (bytes + 255) & ~size_t(255);
    return r;
  };
  int* degseg    = (int*)carve((size_t)L * 4);
  int* cursor    = (int*)carve((size_t)L * 4);
  float* pooled  = (float*)carve((size_t)G * 128 * 4);
  int* rowseg    = (int*)carve((size_t)(L + 1) * 4);
  int* sums      = (int*)carve(4096);
  int* csr_src   = (int*)carve((size_t)Etot * 4);
  int* csr_dst   = (int*)carve((size_t)Etot * 4);
  float* eh      = (float*)carve((size_t)Etot * 4 * 4);                  // per-edge exp, head planes
  unsigned short* Hh = (unsigned short*)carve((size_t)N * 128 * 2);      // bf16 features, head planes
  unsigned short* Xb = (unsigned short*)carve((size_t)N * 128 * 2);      // bf16 layer input (node-major)
  float* as_arr  = (float*)carve((size_t)N * 4 * 4);
  float* ad_arr  = (float*)carve((size_t)N * 4 * 4);

  // zero degseg+cursor+pooled (contiguous carve region, pads included)
  int nz = (int)(((char*)(pooled + (size_t)G * 128) - (char*)degseg) / 4);
  zero_kernel<<<512, 256, 0, stream>>>(degseg, nz);

  // x -> bf16
  xcvt_kernel<<<(N * 64 + 255) / 256, 256, 0, stream>>>(x, Xb, N * 64);

  // CSR build: per-(dst, src-seg) buckets, single fill pass
  int egrid = (Etot + 255) / 256;
  count_kernel<<<egrid, 256, 0, stream>>>(ei, degseg, E, N, nseg);
  int nch = (L + 1023) / 1024;
  scan_block_kernel<<<nch, 1024, 0, stream>>>(degseg, rowseg, sums, L);
  scan_sums_kernel<<<1, 1024, 0, stream>>>(sums, rowseg, nch, L);
  scan_add_kernel<<<nch, 1024, 0, stream>>>(rowseg, sums, L);
  fill_kernel<<<egrid, 256, 0, stream>>>(ei, cursor, rowseg, csr_src, csr_dst, E, N, nseg);

  int ggrid = (N + 63) / 64;
  int nb = (N + 3) / 4;
  int ngrid = 4 * nb;   // 4 heads, head-major block order (phase-locked)

  // layer 0 (K=64)
  gemm_kernel<<<ggrid, 256, 0, stream>>>(Xb, Wm[0], Hh, a_s[0], a_d[0], as_arr, ad_arr, N, 64);
  ecomp_kernel<<<egrid, 256, 0, stream>>>(csr_src, csr_dst, as_arr, ad_arr, eh, Etot);
  agg_kernel<0><<<ngrid, 256, 0, stream>>>(Hh, eh, csr_src, rowseg, bb[0],
                                           Xb, nullptr, nullptr, N, nseg, Etot, nb);
  // layer 1 (K=128)
  gemm_kernel<<<ggrid, 256, 0, stream>>>(Xb, Wm[1], Hh, a_s[1], a_d[1], as_arr, ad_arr, N, 128);
  ecomp_kernel<<<egrid, 256, 0, stream>>>(csr_src, csr_dst, as_arr, ad_arr, eh, Etot);
  agg_kernel<0><<<ngrid, 256, 0, stream>>>(Hh, eh, csr_src, rowseg, bb[1],
                                           Xb, nullptr, nullptr, N, nseg, Etot, nb);
  // layer 2 (K=128), fused pooling
  gemm_kernel<<<ggrid, 256, 0, stream>>>(Xb, Wm[2], Hh, a_s[2], a_d[2], as_arr, ad_arr, N, 128);
  ecomp_kernel<<<egrid, 256, 0, stream>>>(csr_src, csr_dst, as_arr, ad_arr, eh, Etot);
  agg_kernel<1><<<ngrid, 256, 0, stream>>>(Hh, eh, csr_src, rowseg, bb[2],
                                           nullptr, batch, pooled, N, nseg, Etot, nb);

  head_kernel<<<(G + 7) / 8, 256, 0, stream>>>(pooled, fc_w, fc_b, bn_g, bn_b, out, G);
}

// Round 11
// 472.506 us; speedup vs baseline: 1.2265x; 1.2265x over previous
//
#include <hip/hip_runtime.h>
#include <hip/hip_bf16.h>
#include <float.h>

#define NEG 0.2f
#define SEGSHIFT 13   // src-range segments of 8192 nodes

__device__ __forceinline__ float leaky(float x) { return x > 0.0f ? x : NEG * x; }

__device__ __forceinline__ unsigned short f2bf(float f) {
  unsigned x = __float_as_uint(f);
  unsigned r = (x + 0x7fffu + ((x >> 16) & 1u)) >> 16;  // round-to-nearest-even
  return (unsigned short)r;
}

__device__ __forceinline__ float2 bf2f2(unsigned u) {   // u = (ch1<<16)|ch0
  float2 r;
  r.x = __uint_as_float(u << 16);
  r.y = __uint_as_float(u & 0xffff0000u);
  return r;
}

using frag8 = __attribute__((ext_vector_type(8))) short;   // 8 bf16
using f32x4v = __attribute__((ext_vector_type(4))) float;  // 4 fp32 acc

// ---------------------------------------------------------------- utilities
__global__ void zero_kernel(int* __restrict__ p, int n) {
  int i = blockIdx.x * blockDim.x + threadIdx.x;
  int stride = gridDim.x * blockDim.x;
  for (; i < n; i += stride) p[i] = 0;
}

// W [K][128] fp32 -> Wt [128][K] bf16 (transposed, k-contiguous)
__global__ void wcvt_kernel(const float* __restrict__ W, unsigned short* __restrict__ Wt, int K) {
  int i = blockIdx.x * 256 + threadIdx.x;
  if (i >= K * 128) return;
  int k = i >> 7, n = i & 127;
  Wt[n * K + k] = f2bf(W[i]);
}

// count per (dst, src-segment) bucket
__global__ void count_kernel(const int* __restrict__ ei, int* __restrict__ degseg,
                             int E, int N, int nseg) {
  int i = blockIdx.x * blockDim.x + threadIdx.x;
  if (i >= E + N) return;
  int src, dst;
  if (i < E) { src = ei[i]; dst = ei[E + i]; } else { src = dst = i - E; }
  atomicAdd(&degseg[(size_t)dst * nseg + (src >> SEGSHIFT)], 1);
}

__global__ __launch_bounds__(1024) void scan_block_kernel(const int* __restrict__ deg,
                                                          int* __restrict__ row_start,
                                                          int* __restrict__ sums, int n) {
  __shared__ int buf[1024];
  int t = threadIdx.x;
  int idx = blockIdx.x * 1024 + t;
  int x = (idx < n) ? deg[idx] : 0;
  int v = x;
  buf[t] = v;
  __syncthreads();
  for (int off = 1; off < 1024; off <<= 1) {
    int a = (t >= off) ? buf[t - off] : 0;
    __syncthreads();
    v += a;
    buf[t] = v;
    __syncthreads();
  }
  if (idx < n) row_start[idx] = v - x;  // local exclusive
  if (t == 1023) sums[blockIdx.x] = v;  // chunk total
}

__global__ __launch_bounds__(1024) void scan_sums_kernel(int* __restrict__ sums,
                                                         int* __restrict__ row_start,
                                                         int nch, int n) {
  __shared__ int buf[1024];
  int t = threadIdx.x;
  int x = (t < nch) ? sums[t] : 0;
  int v = x;
  buf[t] = v;
  __syncthreads();
  for (int off = 1; off < 1024; off <<= 1) {
    int a = (t >= off) ? buf[t - off] : 0;
    __syncthreads();
    v += a;
    buf[t] = v;
    __syncthreads();
  }
  if (t < nch) sums[t] = v - x;        // exclusive chunk offsets
  if (t == 1023) row_start[n] = v;     // grand total
}

__global__ __launch_bounds__(1024) void scan_add_kernel(int* __restrict__ row_start,
                                                        const int* __restrict__ sums, int n) {
  int idx = blockIdx.x * 1024 + threadIdx.x;
  if (idx < n) row_start[idx] += sums[blockIdx.x];
}

// single-pass fill into (dst, src-segment) buckets
__global__ void fill_kernel(const int* __restrict__ ei, int* __restrict__ cursor,
                            const int* __restrict__ rowseg, int* __restrict__ csr_src,
                            int* __restrict__ csr_dst, int E, int N, int nseg) {
  int i = blockIdx.x * blockDim.x + threadIdx.x;
  if (i >= E + N) return;
  int src, dst;
  if (i < E) { src = ei[i]; dst = ei[E + i]; } else { src = dst = i - E; }
  size_t b = (size_t)dst * nseg + (src >> SEGSHIFT);
  int pos = atomicAdd(&cursor[b], 1);
  int slot = rowseg[b] + pos;
  csr_src[slot] = src;
  csr_dst[slot] = dst;
}

// ---------------------------------------------------------------- MFMA GEMM  Hb = bf16(X @ W), fused alpha dots
// Wt: bf16 [128][K] pre-transposed. FP32IN: stage-converts fp32 input rows.
template <int FP32IN>
__global__ __launch_bounds__(256) void gemm_kernel(const void* __restrict__ Xin,
                                                   const unsigned short* __restrict__ Wtg,
                                                   unsigned short* __restrict__ Hb,
                                                   const float* __restrict__ a_src,
                                                   const float* __restrict__ a_dst,
                                                   float* __restrict__ as_arr,
                                                   float* __restrict__ ad_arr,
                                                   int nrows, int K) {
  __shared__ unsigned short Wt[128][136];  // [n][k] bf16
  __shared__ unsigned short Xs[64][136];   // [row][k] bf16; reused for C transpose
  int t = threadIdx.x;
  int wave = t >> 6, lane = t & 63;
  int n0 = lane & 15, quad = lane >> 4;
  int row0 = blockIdx.x * 64, wrow = wave * 16;

  // stage Wt from pre-converted bf16 (16B chunks)
  for (int idx = t; idx < (K * 128) / 8; idx += 256) {
    int n = idx / (K >> 3), c8 = idx % (K >> 3);
    *(uint4*)(&Wt[n][c8 * 8]) = *(const uint4*)(Wtg + (size_t)n * K + c8 * 8);
  }
  int rowElems = K >> 3;
  if (FP32IN) {
    const float* Xf = (const float*)Xin;
    for (int idx = t; idx < 64 * K; idx += 256) {
      int r = idx / K, k = idx % K;
      int gr = row0 + r;
      Xs[r][k] = f2bf(gr < nrows ? Xf[(size_t)gr * K + k] : 0.f);
    }
  } else {
    const unsigned short* Xb = (const unsigned short*)Xin;
    for (int idx = t; idx < 64 * rowElems; idx += 256) {
      int r = idx / rowElems, c8 = idx % rowElems;
      int gr = row0 + r;
      uint4 v = make_uint4(0, 0, 0, 0);
      if (gr < nrows) v = *(const uint4*)(Xb + (size_t)gr * K + c8 * 8);
      *(uint4*)(&Xs[r][c8 * 8]) = v;
    }
  }
  __syncthreads();

  f32x4v acc[8];
#pragma unroll
  for (int c = 0; c < 8; ++c) acc[c] = (f32x4v){0.f, 0.f, 0.f, 0.f};

  for (int kb = 0; kb < K; kb += 32) {
    frag8 a = *(const frag8*)(&Xs[wrow + n0][kb + quad * 8]);
#pragma unroll
    for (int c = 0; c < 8; ++c) {
      frag8 b = *(const frag8*)(&Wt[c * 16 + n0][kb + quad * 8]);
      acc[c] = __builtin_amdgcn_mfma_f32_16x16x32_bf16(a, b, acc[c], 0, 0, 0);
    }
  }

  float asv[8], adv[8];
#pragma unroll
  for (int c = 0; c < 8; ++c) {
    asv[c] = a_src[c * 16 + n0];
    adv[c] = a_dst[c * 16 + n0];
  }
#pragma unroll
  for (int r = 0; r < 4; ++r) {
    float ps[4] = {0.f, 0.f, 0.f, 0.f}, pd[4] = {0.f, 0.f, 0.f, 0.f};
#pragma unroll
    for (int c = 0; c < 8; ++c) {
      int h = c >> 1;
      ps[h] += acc[c][r] * asv[c];
      pd[h] += acc[c][r] * adv[c];
    }
#pragma unroll
    for (int off = 1; off < 16; off <<= 1) {
#pragma unroll
      for (int h = 0; h < 4; ++h) {
        ps[h] += __shfl_xor(ps[h], off);
        pd[h] += __shfl_xor(pd[h], off);
      }
    }
    if (n0 == 0) {
      int m = row0 + wrow + quad * 4 + r;
      if (m < nrows) {
#pragma unroll
        for (int h = 0; h < 4; ++h) {
          as_arr[(size_t)m * 4 + h] = ps[h];
          ad_arr[(size_t)m * 4 + h] = pd[h];
        }
      }
    }
  }

  __syncthreads();
#pragma unroll
  for (int c = 0; c < 8; ++c)
#pragma unroll
    for (int r = 0; r < 4; ++r)
      Xs[wrow + quad * 4 + r][c * 16 + n0] = f2bf(acc[c][r]);
  __syncthreads();
  for (int idx = t; idx < 64 * 16; idx += 256) {
    int r = idx >> 4, c8 = idx & 15;
    int gr = row0 + r;
    if (gr < nrows)
      *(uint4*)(Hb + (size_t)gr * 128 + c8 * 8) = *(const uint4*)(&Xs[r][c8 * 8]);
  }
}

// ---------------------------------------------------------------- per-edge exp(leaky(logit)) for all 4 heads
__global__ __launch_bounds__(256) void ecomp_kernel(const int* __restrict__ csr_src,
                                                    const int* __restrict__ csr_dst,
                                                    const float* __restrict__ as_arr,
                                                    const float* __restrict__ ad_arr,
                                                    float* __restrict__ earr, int Etot) {
  int i = blockIdx.x * 256 + threadIdx.x;
  if (i >= Etot) return;
  int s = csr_src[i];
  int d = csr_dst[i];
  float4 a = *(const float4*)(as_arr + (size_t)s * 4);
  float4 b = *(const float4*)(ad_arr + (size_t)d * 4);
  float4 e;
  e.x = __expf(fminf(leaky(a.x + b.x), 80.f));
  e.y = __expf(fminf(leaky(a.y + b.y), 80.f));
  e.z = __expf(fminf(leaky(a.z + b.z), 80.f));
  e.w = __expf(fminf(leaky(a.w + b.w), 80.f));
  *(float4*)(earr + (size_t)i * 4) = e;
}

// ---------------------------------------------------------------- aggregation (R5/R9-verified form)
template <int POOL>
__global__ __launch_bounds__(256) void agg_kernel(const unsigned short* __restrict__ Hb,
                                                  const float* __restrict__ earr,
                                                  const int* __restrict__ csr_src,
                                                  const int* __restrict__ rowseg,
                                                  const float* __restrict__ bias,
                                                  unsigned short* __restrict__ xnext,
                                                  const int* __restrict__ batch,
                                                  float* __restrict__ pooled,
                                                  int N, int nseg) {
  int wid = threadIdx.x >> 6;
  int lane = threadIdx.x & 63;
  int n = blockIdx.x * 4 + wid;
  if (n >= N) return;
  int rs = rowseg[(size_t)n * nseg];
  int re = rowseg[(size_t)n * nseg + nseg];
  int head = lane >> 4;

  const unsigned* hp = (const unsigned*)Hb + lane;
  const float* ep = earr + head;
  float denom = 0.f, acc0 = 0.f, acc1 = 0.f;
  int i = rs;
  for (; i + 4 <= re; i += 4) {
    int s0 = csr_src[i], s1 = csr_src[i + 1], s2 = csr_src[i + 2], s3 = csr_src[i + 3];
    float e0 = ep[(size_t)i * 4];
    float e1 = ep[(size_t)(i + 1) * 4];
    float e2 = ep[(size_t)(i + 2) * 4];
    float e3 = ep[(size_t)(i + 3) * 4];
    unsigned u0 = hp[(size_t)s0 * 64];
    unsigned u1 = hp[(size_t)s1 * 64];
    unsigned u2 = hp[(size_t)s2 * 64];
    unsigned u3 = hp[(size_t)s3 * 64];
    denom += (e0 + e1) + (e2 + e3);
    float2 f;
    f = bf2f2(u0); acc0 += e0 * f.x; acc1 += e0 * f.y;
    f = bf2f2(u1); acc0 += e1 * f.x; acc1 += e1 * f.y;
    f = bf2f2(u2); acc0 += e2 * f.x; acc1 += e2 * f.y;
    f = bf2f2(u3); acc0 += e3 * f.x; acc1 += e3 * f.y;
  }
  for (; i < re; ++i) {
    int s0 = csr_src[i];
    float e0 = ep[(size_t)i * 4];
    unsigned u0 = hp[(size_t)s0 * 64];
    float2 f = bf2f2(u0);
    denom += e0;
    acc0 += e0 * f.x;
    acc1 += e0 * f.y;
  }
  float inv = 1.0f / (denom + 1e-16f);
  float2 bv = *(const float2*)(bias + 2 * lane);
  float v0 = leaky(acc0 * inv + bv.x);
  float v1 = leaky(acc1 * inv + bv.y);
  if (POOL) {
    int g = batch[n];
    atomicAdd(&pooled[(size_t)g * 128 + 2 * lane], v0);
    atomicAdd(&pooled[(size_t)g * 128 + 2 * lane + 1], v1);
  } else {
    unsigned pk = ((unsigned)f2bf(v1) << 16) | (unsigned)f2bf(v0);
    ((unsigned*)xnext)[(size_t)n * 64 + lane] = pk;
  }
}

// ---------------------------------------------------------------- head
__global__ void head_kernel(const float* __restrict__ pooled, const float* __restrict__ fc_w,
                            const float* __restrict__ fc_b, const float* __restrict__ bn_g,
                            const float* __restrict__ bn_b, float* __restrict__ out, int G) {
  int t = threadIdx.x;
  int g = blockIdx.x * 8 + (t >> 5);
  int j = t & 31;
  if (g >= G) return;
  const float* pr = pooled + (size_t)g * 128;
  float acc = 0.f;
#pragma unroll 8
  for (int k = 0; k < 128; ++k) acc += pr[k] * fc_w[k * 32 + j];
  const float inv = 0.9999950000374997f;  // 1/sqrt(1+1e-5)
  out[g * 32 + j] = bn_g[j] * (acc + fc_b[j]) * inv + bn_b[j];
}

// ---------------------------------------------------------------- launch
extern "C" void kernel_launch(void* const* d_in, const int* in_sizes, int n_in,
                              void* d_out, int out_size, void* d_ws, size_t ws_size,
                              hipStream_t stream) {
  const float* x = (const float*)d_in[0];
  const int* ei = (const int*)d_in[1];
  const int* batch = (const int*)d_in[2];
  const float* Wm[3] = {(const float*)d_in[3], (const float*)d_in[7], (const float*)d_in[11]};
  const float* a_s[3] = {(const float*)d_in[4], (const float*)d_in[8], (const float*)d_in[12]};
  const float* a_d[3] = {(const float*)d_in[5], (const float*)d_in[9], (const float*)d_in[13]};
  const float* bb[3] = {(const float*)d_in[6], (const float*)d_in[10], (const float*)d_in[14]};
  const float* fc_w = (const float*)d_in[15];
  const float* fc_b = (const float*)d_in[16];
  const float* bn_g = (const float*)d_in[17];
  const float* bn_b = (const float*)d_in[18];
  float* out = (float*)d_out;

  int N = in_sizes[0] / 64;
  int E = in_sizes[1] / 2;
  int G = out_size / 32;
  int Etot = E + N;
  int nseg = ((N - 1) >> SEGSHIFT) + 1;
  int L = N * nseg;   // bucket count

  char* p = (char*)d_ws;
  auto carve = [&](size_t bytes) {
    char* r = p;
    p += (bytes + 255) & ~size_t(255);
    return r;
  };
  int* degseg    = (int*)carve((size_t)L * 4);
  int* cursor    = (int*)carve((size_t)L * 4);
  float* pooled  = (float*)carve((size_t)G * 128 * 4);
  int* rowseg    = (int*)carve((size_t)(L + 1) * 4);
  int* sums      = (int*)carve(4096);
  int* csr_src   = (int*)carve((size_t)Etot * 4);
  int* csr_dst   = (int*)carve((size_t)Etot * 4);
  float* earr    = (float*)carve((size_t)Etot * 4 * 4);                  // per-edge exp, 4 heads
  unsigned short* Hb  = (unsigned short*)carve((size_t)N * 128 * 2);     // bf16 features
  unsigned short* Xb  = (unsigned short*)carve((size_t)N * 128 * 2);     // bf16 layer input
  unsigned short* Wt0 = (unsigned short*)carve(64 * 128 * 2);            // bf16 W^T per layer
  unsigned short* Wt1 = (unsigned short*)carve(128 * 128 * 2);
  unsigned short* Wt2 = (unsigned short*)carve(128 * 128 * 2);
  float* as_arr  = (float*)carve((size_t)N * 4 * 4);
  float* ad_arr  = (float*)carve((size_t)N * 4 * 4);

  // zero degseg+cursor+pooled (contiguous carve region, pads included)
  int nz = (int)(((char*)(pooled + (size_t)G * 128) - (char*)degseg) / 4);
  zero_kernel<<<512, 256, 0, stream>>>(degseg, nz);

  // pre-transpose/convert weights
  wcvt_kernel<<<(64 * 128 + 255) / 256, 256, 0, stream>>>(Wm[0], Wt0, 64);
  wcvt_kernel<<<(128 * 128 + 255) / 256, 256, 0, stream>>>(Wm[1], Wt1, 128);
  wcvt_kernel<<<(128 * 128 + 255) / 256, 256, 0, stream>>>(Wm[2], Wt2, 128);

  // CSR build: per-(dst, src-seg) buckets, single fill pass
  int egrid = (Etot + 255) / 256;
  count_kernel<<<egrid, 256, 0, stream>>>(ei, degseg, E, N, nseg);
  int nch = (L + 1023) / 1024;
  scan_block_kernel<<<nch, 1024, 0, stream>>>(degseg, rowseg, sums, L);
  scan_sums_kernel<<<1, 1024, 0, stream>>>(sums, rowseg, nch, L);
  scan_add_kernel<<<nch, 1024, 0, stream>>>(rowseg, sums, L);
  fill_kernel<<<egrid, 256, 0, stream>>>(ei, cursor, rowseg, csr_src, csr_dst, E, N, nseg);

  int ggrid = (N + 63) / 64;
  int ngrid = (N + 3) / 4;

  // layer 0 (K=64, fp32 input direct)
  gemm_kernel<1><<<ggrid, 256, 0, stream>>>(x, Wt0, Hb, a_s[0], a_d[0], as_arr, ad_arr, N, 64);
  ecomp_kernel<<<egrid, 256, 0, stream>>>(csr_src, csr_dst, as_arr, ad_arr, earr, Etot);
  agg_kernel<0><<<ngrid, 256, 0, stream>>>(Hb, earr, csr_src, rowseg, bb[0],
                                           Xb, nullptr, nullptr, N, nseg);
  // layer 1 (K=128)
  gemm_kernel<0><<<ggrid, 256, 0, stream>>>(Xb, Wt1, Hb, a_s[1], a_d[1], as_arr, ad_arr, N, 128);
  ecomp_kernel<<<egrid, 256, 0, stream>>>(csr_src, csr_dst, as_arr, ad_arr, earr, Etot);
  agg_kernel<0><<<ngrid, 256, 0, stream>>>(Hb, earr, csr_src, rowseg, bb[1],
                                           Xb, nullptr, nullptr, N, nseg);
  // layer 2 (K=128), fused pooling
  gemm_kernel<0><<<ggrid, 256, 0, stream>>>(Xb, Wt2, Hb, a_s[2], a_d[2], as_arr, ad_arr, N, 128);
  ecomp_kernel<<<egrid, 256, 0, stream>>>(csr_src, csr_dst, as_arr, ad_arr, earr, Etot);
  agg_kernel<1><<<ngrid, 256, 0, stream>>>(Hb, earr, csr_src, rowseg, bb[2],
                                           nullptr, batch, pooled, N, nseg);

  head_kernel<<<(G + 7) / 8, 256, 0, stream>>>(pooled, fc_w, fc_b, bn_g, bn_b, out, G);
}